// Round 1
// baseline (100.353 us; speedup 1.0000x reference)
//
#include <hip/hip_runtime.h>
#include <hip/hip_bf16.h>

#define NPTS 262144
#define EMB  256
#define RES  512
#define NROWS (4 * RES)   // 2048 table rows total

// ---------------------------------------------------------------------------
// Kernel 1: T2[a,i,o] = (30/4) * sum_e tables[a,i,e] * W1[o,e], stored bf16.
// Folds the W0=30 sine frequency and the 1/4 axis-mean into the table.
// 256 blocks x 256 threads; each block handles 8 table rows staged in LDS.
// ---------------------------------------------------------------------------
__global__ __launch_bounds__(256) void t2_precompute_kernel(
    const float* __restrict__ tables,   // [4][512][256]
    const float* __restrict__ W1,       // [256][256] (W1[o][e])
    __hip_bfloat16* __restrict__ T2)    // [2048][256]
{
    __shared__ __align__(16) float arow[8][EMB];
    const int row0 = blockIdx.x * 8;
    const int o = threadIdx.x;

    #pragma unroll
    for (int r = 0; r < 8; ++r)
        arow[r][o] = tables[(row0 + r) * EMB + o];
    __syncthreads();

    float acc[8] = {0.f, 0.f, 0.f, 0.f, 0.f, 0.f, 0.f, 0.f};
    const float4* __restrict__ w1v = reinterpret_cast<const float4*>(W1 + o * EMB);
    for (int ec = 0; ec < EMB / 4; ++ec) {
        const float4 w4 = w1v[ec];
        #pragma unroll
        for (int r = 0; r < 8; ++r) {
            const float4 a4 = *reinterpret_cast<const float4*>(&arow[r][ec * 4]);
            acc[r] = fmaf(w4.x, a4.x, acc[r]);
            acc[r] = fmaf(w4.y, a4.y, acc[r]);
            acc[r] = fmaf(w4.z, a4.z, acc[r]);
            acc[r] = fmaf(w4.w, a4.w, acc[r]);
        }
    }
    #pragma unroll
    for (int r = 0; r < 8; ++r)
        T2[(row0 + r) * EMB + o] = __float2bfloat16(7.5f * acc[r]);
}

// ---------------------------------------------------------------------------
// Kernel 2: per-point pipeline. One wave64 per point; lane owns 4 emb dims.
//   arg[e] = sum_a [(1-w_a)*T2[a,i0_a,e] + w_a*T2[a,i0_a+1,e]] + 30*b1[e]
//   h = sin(arg);  out[j] = sum_e h[e]*W2[j,e] + b2[j]
// ---------------------------------------------------------------------------
__global__ __launch_bounds__(256) void eval_kernel(
    const float* __restrict__ coords,          // [N][2]
    const __hip_bfloat16* __restrict__ T2,     // [2048][256]
    const float* __restrict__ b1,              // [256]
    const float* __restrict__ W2,              // [3][256]
    const float* __restrict__ b2,              // [3]
    float* __restrict__ out)                   // [N][3]
{
    const int lane   = threadIdx.x & 63;
    const int wave   = (int)((blockIdx.x * blockDim.x + threadIdx.x) >> 6);
    const int nwaves = (int)((gridDim.x * blockDim.x) >> 6);
    const int e0 = lane * 4;

    // Hoisted per-lane constants (reused across all points of this wave)
    const float4 b1v = *reinterpret_cast<const float4*>(b1 + e0);
    const float bs0 = 30.f * b1v.x, bs1 = 30.f * b1v.y;
    const float bs2 = 30.f * b1v.z, bs3 = 30.f * b1v.w;
    const float4 w20 = *reinterpret_cast<const float4*>(W2 + 0 * EMB + e0);
    const float4 w21 = *reinterpret_cast<const float4*>(W2 + 1 * EMB + e0);
    const float4 w22 = *reinterpret_cast<const float4*>(W2 + 2 * EMB + e0);
    const float ob0 = b2[0], ob1 = b2[1], ob2 = b2[2];

    for (int p = wave; p < NPTS; p += nwaves) {
        float x = coords[2 * p];
        float y = coords[2 * p + 1];
        x = fminf(fmaxf(x, -1.f), 1.f);
        y = fminf(fmaxf(y, -1.f), 1.f);
        const float axes[4] = {x, y, 0.5f * (x + y), 0.5f * (x - y)};

        float a0 = 0.f, a1 = 0.f, a2 = 0.f, a3 = 0.f;
        #pragma unroll
        for (int a = 0; a < 4; ++a) {
            float c = fminf(fmaxf(axes[a], -1.f), 0.999f);
            float t = fmaf(c, 255.5f, 255.5f);   // (0.5c+0.5)*511
            float fi = floorf(t);
            float w = t - fi;
            float omw = 1.f - w;
            int i0 = (int)fi;
            // row gather: 8 bytes (4 bf16) per lane, coalesced 512B per wave
            const uint2* __restrict__ rp =
                reinterpret_cast<const uint2*>(T2 + ((a << 9) + i0) * EMB) + lane;
            const uint2 u0 = rp[0];
            const uint2 u1 = rp[EMB / 4];   // next row (+256 bf16 = +64 uint2)

            a0 = fmaf(__uint_as_float(u0.x << 16),          omw, a0);
            a0 = fmaf(__uint_as_float(u1.x << 16),          w,   a0);
            a1 = fmaf(__uint_as_float(u0.x & 0xffff0000u),  omw, a1);
            a1 = fmaf(__uint_as_float(u1.x & 0xffff0000u),  w,   a1);
            a2 = fmaf(__uint_as_float(u0.y << 16),          omw, a2);
            a2 = fmaf(__uint_as_float(u1.y << 16),          w,   a2);
            a3 = fmaf(__uint_as_float(u0.y & 0xffff0000u),  omw, a3);
            a3 = fmaf(__uint_as_float(u1.y & 0xffff0000u),  w,   a3);
        }

        const float h0 = __sinf(a0 + bs0);
        const float h1 = __sinf(a1 + bs1);
        const float h2 = __sinf(a2 + bs2);
        const float h3 = __sinf(a3 + bs3);

        float q0 = fmaf(h0, w20.x, fmaf(h1, w20.y, fmaf(h2, w20.z, h3 * w20.w)));
        float q1 = fmaf(h0, w21.x, fmaf(h1, w21.y, fmaf(h2, w21.z, h3 * w21.w)));
        float q2 = fmaf(h0, w22.x, fmaf(h1, w22.y, fmaf(h2, w22.z, h3 * w22.w)));

        #pragma unroll
        for (int off = 32; off > 0; off >>= 1) {
            q0 += __shfl_xor(q0, off, 64);
            q1 += __shfl_xor(q1, off, 64);
            q2 += __shfl_xor(q2, off, 64);
        }

        if (lane == 0) {
            out[3 * p + 0] = q0 + ob0;
            out[3 * p + 1] = q1 + ob1;
            out[3 * p + 2] = q2 + ob2;
        }
    }
}

extern "C" void kernel_launch(void* const* d_in, const int* in_sizes, int n_in,
                              void* d_out, int out_size, void* d_ws, size_t ws_size,
                              hipStream_t stream) {
    const float* coords = (const float*)d_in[0];
    const float* tables = (const float*)d_in[1];
    const float* W1     = (const float*)d_in[2];
    const float* b1     = (const float*)d_in[3];
    const float* W2     = (const float*)d_in[4];
    const float* b2     = (const float*)d_in[5];
    float* out = (float*)d_out;

    __hip_bfloat16* T2 = (__hip_bfloat16*)d_ws;   // 2048*256*2B = 1 MiB scratch

    hipLaunchKernelGGL(t2_precompute_kernel, dim3(NROWS / 8), dim3(256), 0, stream,
                       tables, W1, T2);
    hipLaunchKernelGGL(eval_kernel, dim3(1024), dim3(256), 0, stream,
                       coords, T2, b1, W2, b2, out);
}

// Round 2
// 68.907 us; speedup vs baseline: 1.4563x; 1.4563x over previous
//
#include <hip/hip_runtime.h>
#include <hip/hip_bf16.h>
#include <hip/hip_fp16.h>

#define NPTS 262144
#define EMB  256
#define RES  512
#define NROWS (4 * RES)   // 2048 table rows total

typedef _Float16 half_t;
typedef __attribute__((ext_vector_type(8))) _Float16 half8;

// ---------------------------------------------------------------------------
// Kernel 1: T2[a,i,o] = (30/4)/(2pi) * sum_e tables[a,i,e] * W1[o,e], fp16.
// Folds W0=30, the 1/4 axis-mean, AND the 1/(2pi) rev-conversion for v_sin.
// ---------------------------------------------------------------------------
__global__ __launch_bounds__(256) void t2_precompute_kernel(
    const float* __restrict__ tables,   // [4][512][256]
    const float* __restrict__ W1,       // [256][256] (W1[o][e])
    half_t* __restrict__ T2)            // [2048][256] fp16
{
    __shared__ __align__(16) float arow[8][EMB];
    const int row0 = blockIdx.x * 8;
    const int o = threadIdx.x;

    #pragma unroll
    for (int r = 0; r < 8; ++r)
        arow[r][o] = tables[(row0 + r) * EMB + o];
    __syncthreads();

    float acc[8] = {0.f, 0.f, 0.f, 0.f, 0.f, 0.f, 0.f, 0.f};
    const float4* __restrict__ w1v = reinterpret_cast<const float4*>(W1 + o * EMB);
    for (int ec = 0; ec < EMB / 4; ++ec) {
        const float4 w4 = w1v[ec];
        #pragma unroll
        for (int r = 0; r < 8; ++r) {
            const float4 a4 = *reinterpret_cast<const float4*>(&arow[r][ec * 4]);
            acc[r] = fmaf(w4.x, a4.x, acc[r]);
            acc[r] = fmaf(w4.y, a4.y, acc[r]);
            acc[r] = fmaf(w4.z, a4.z, acc[r]);
            acc[r] = fmaf(w4.w, a4.w, acc[r]);
        }
    }
    const float s = 7.5f * 0.15915494309189535f;   // (30/4) / (2*pi)
    #pragma unroll
    for (int r = 0; r < 8; ++r)
        T2[(row0 + r) * EMB + o] = (half_t)(s * acc[r]);
}

// ---------------------------------------------------------------------------
// Kernel 2: half-wave (32 lanes) per point, 8 dims per lane, 2 points/wave/iter.
//   acc[d] (revolutions) = sum_a lerp(T2 rows) + 30*b1/(2pi)
//   h = v_sin(v_fract(acc));  out[j] = sum_dims h*W2[j] + b2[j]
// ---------------------------------------------------------------------------
__global__ __launch_bounds__(256, 8) void eval_kernel(
    const float* __restrict__ coords,      // [N][2]
    const half_t* __restrict__ T2,         // [2048][256] fp16
    const float* __restrict__ b1,          // [256]
    const float* __restrict__ W2,          // [3][256]
    const float* __restrict__ b2,          // [3]
    float* __restrict__ out)               // [N][3]
{
    const int lane = threadIdx.x & 63;
    const int hf   = lane >> 5;            // which point of the pair
    const int l    = lane & 31;            // lane within half-wave
    const int e0   = l * 8;                // 8 embedding dims per lane

    const int wave   = blockIdx.x * 4 + (threadIdx.x >> 6);
    const int nwaves = gridDim.x * 4;

    // Hoisted per-lane constants
    const float sb = 30.f * 0.15915494309189535f;  // bias scale, revolutions
    float bias[8];
    float w2r[3][8];
    #pragma unroll
    for (int d = 0; d < 8; ++d) bias[d] = sb * b1[e0 + d];
    #pragma unroll
    for (int j = 0; j < 3; ++j)
        #pragma unroll
        for (int d = 0; d < 8; ++d) w2r[j][d] = W2[j * EMB + e0 + d];
    const float ob0 = b2[0], ob1 = b2[1], ob2 = b2[2];

    const char* __restrict__ T2b = reinterpret_cast<const char*>(T2);

    for (int pp = wave; pp < NPTS / 2; pp += nwaves) {
        const int p = 2 * pp + hf;
        const float2 cf = *reinterpret_cast<const float2*>(coords + 2 * p);
        const float x = fminf(fmaxf(cf.x, -1.f), 1.f);
        const float y = fminf(fmaxf(cf.y, -1.f), 1.f);

        float acc[8];
        #pragma unroll
        for (int d = 0; d < 8; ++d) acc[d] = bias[d];

        #pragma unroll
        for (int a = 0; a < 4; ++a) {
            float c = (a == 0) ? x : (a == 1) ? y
                    : (a == 2) ? 0.5f * (x + y) : 0.5f * (x - y);
            c = fminf(fmaxf(c, -1.f), 0.999f);
            const float t  = fmaf(c, 255.5f, 255.5f);   // (0.5c+0.5)*511
            const float fi = floorf(t);
            const float w  = t - fi;
            const float omw = 1.f - w;
            // byte offset: ((a*512 + i0) * 256 dims * 2B) + e0*2B
            const int rowbyte = (((a << 9) + (int)fi) << 9) + (e0 << 1);
            const half8 v0 = *reinterpret_cast<const half8*>(T2b + rowbyte);
            const half8 v1 = *reinterpret_cast<const half8*>(T2b + rowbyte + 512);
            #pragma unroll
            for (int d = 0; d < 8; ++d) {
                acc[d] = fmaf((float)v0[d], omw, acc[d]);   // v_fma_mix_f32
                acc[d] = fmaf((float)v1[d], w,   acc[d]);
            }
        }

        float q0 = 0.f, q1 = 0.f, q2 = 0.f;
        #pragma unroll
        for (int d = 0; d < 8; ++d) {
            const float h = __builtin_amdgcn_sinf(__builtin_amdgcn_fractf(acc[d]));
            q0 = fmaf(h, w2r[0][d], q0);
            q1 = fmaf(h, w2r[1][d], q1);
            q2 = fmaf(h, w2r[2][d], q2);
        }

        // 5-level butterfly within each 32-lane half
        #pragma unroll
        for (int off = 16; off > 0; off >>= 1) {
            q0 += __shfl_xor(q0, off, 64);
            q1 += __shfl_xor(q1, off, 64);
            q2 += __shfl_xor(q2, off, 64);
        }

        if (l == 0) {
            out[3 * p + 0] = q0 + ob0;
            out[3 * p + 1] = q1 + ob1;
            out[3 * p + 2] = q2 + ob2;
        }
    }
}

extern "C" void kernel_launch(void* const* d_in, const int* in_sizes, int n_in,
                              void* d_out, int out_size, void* d_ws, size_t ws_size,
                              hipStream_t stream) {
    const float* coords = (const float*)d_in[0];
    const float* tables = (const float*)d_in[1];
    const float* W1     = (const float*)d_in[2];
    const float* b1     = (const float*)d_in[3];
    const float* W2     = (const float*)d_in[4];
    const float* b2     = (const float*)d_in[5];
    float* out = (float*)d_out;

    half_t* T2 = (half_t*)d_ws;   // 2048*256*2B = 1 MiB scratch

    hipLaunchKernelGGL(t2_precompute_kernel, dim3(NROWS / 8), dim3(256), 0, stream,
                       tables, W1, T2);
    hipLaunchKernelGGL(eval_kernel, dim3(2048), dim3(256), 0, stream,
                       coords, T2, b1, W2, b2, out);
}

// Round 3
// 66.364 us; speedup vs baseline: 1.5122x; 1.0383x over previous
//
#include <hip/hip_runtime.h>
#include <hip/hip_bf16.h>
#include <hip/hip_fp16.h>

#define NPTS 262144
#define EMB  256
#define RES  512
#define NROWS (4 * RES)   // 2048 table rows total

typedef _Float16 half_t;
typedef __attribute__((ext_vector_type(8))) _Float16 half8;

// ---------------------------------------------------------------------------
// Kernel 1: T2[a,i,o] = (30/4)/(2pi) * sum_e tables[a,i,e] * W1[o,e], fp16.
// Folds W0=30, the 1/4 axis-mean, AND the 1/(2pi) rev-conversion for v_sin.
// ---------------------------------------------------------------------------
__global__ __launch_bounds__(256) void t2_precompute_kernel(
    const float* __restrict__ tables,   // [4][512][256]
    const float* __restrict__ W1,       // [256][256] (W1[o][e])
    half_t* __restrict__ T2)            // [2048][256] fp16
{
    __shared__ __align__(16) float arow[8][EMB];
    const int row0 = blockIdx.x * 8;
    const int o = threadIdx.x;

    #pragma unroll
    for (int r = 0; r < 8; ++r)
        arow[r][o] = tables[(row0 + r) * EMB + o];
    __syncthreads();

    float acc[8] = {0.f, 0.f, 0.f, 0.f, 0.f, 0.f, 0.f, 0.f};
    const float4* __restrict__ w1v = reinterpret_cast<const float4*>(W1 + o * EMB);
    for (int ec = 0; ec < EMB / 4; ++ec) {
        const float4 w4 = w1v[ec];
        #pragma unroll
        for (int r = 0; r < 8; ++r) {
            const float4 a4 = *reinterpret_cast<const float4*>(&arow[r][ec * 4]);
            acc[r] = fmaf(w4.x, a4.x, acc[r]);
            acc[r] = fmaf(w4.y, a4.y, acc[r]);
            acc[r] = fmaf(w4.z, a4.z, acc[r]);
            acc[r] = fmaf(w4.w, a4.w, acc[r]);
        }
    }
    const float s = 7.5f * 0.15915494309189535f;   // (30/4) / (2*pi)
    #pragma unroll
    for (int r = 0; r < 8; ++r)
        T2[(row0 + r) * EMB + o] = (half_t)(s * acc[r]);
}

// ---------------------------------------------------------------------------
// Kernel 2: 16 lanes per point, 16 dims per lane, 4 points per wave.
//   acc_h (fp16 packed, revolutions) = sum_a lerp(T2 rows)
//   arg = (f32)acc_h + 30*b1/(2pi);  h = v_sin(v_fract(arg))
//   out[j] = sum_dims h * W2[j] + b2[j]   (W2 packed fp16 -> v_fma_mix)
// ---------------------------------------------------------------------------
__global__ __launch_bounds__(256) void eval_kernel(
    const float* __restrict__ coords,      // [N][2]
    const half_t* __restrict__ T2,         // [2048][256] fp16
    const float* __restrict__ b1,          // [256]
    const float* __restrict__ W2,          // [3][256]
    const float* __restrict__ b2,          // [3]
    float* __restrict__ out)               // [N][3]
{
    const int lane = threadIdx.x & 63;
    const int g    = lane >> 4;            // point slot 0..3 within wave
    const int l16  = lane & 15;            // lane within 16-lane group
    const int e0   = l16 * 16;             // 16 embedding dims per lane

    const int wave   = blockIdx.x * 4 + (threadIdx.x >> 6);
    const int nwaves = gridDim.x * 4;

    // Hoisted per-lane constants (once per wave, amortized over the loop)
    const float sb = 30.f * 0.15915494309189535f;  // bias scale -> revolutions
    float bias[16];
    #pragma unroll
    for (int d = 0; d < 16; ++d) bias[d] = sb * b1[e0 + d];

    half8 w2h[3][2];
    #pragma unroll
    for (int j = 0; j < 3; ++j)
        #pragma unroll
        for (int k = 0; k < 2; ++k)
            #pragma unroll
            for (int i = 0; i < 8; ++i)
                w2h[j][k][i] = (half_t)W2[j * EMB + e0 + k * 8 + i];

    const float ob0 = b2[0], ob1 = b2[1], ob2 = b2[2];
    const char* __restrict__ T2b = reinterpret_cast<const char*>(T2);

    for (int pq = wave; pq < NPTS / 4; pq += nwaves) {
        const int p = 4 * pq + g;
        const float2 cf = *reinterpret_cast<const float2*>(coords + 2 * p);
        const float x = fminf(fmaxf(cf.x, -1.f), 1.f);
        const float y = fminf(fmaxf(cf.y, -1.f), 1.f);

        half8 accA = {0, 0, 0, 0, 0, 0, 0, 0};   // dims e0..e0+7
        half8 accB = {0, 0, 0, 0, 0, 0, 0, 0};   // dims e0+8..e0+15

        #pragma unroll
        for (int a = 0; a < 4; ++a) {
            float c = (a == 0) ? x : (a == 1) ? y
                    : (a == 2) ? 0.5f * (x + y) : 0.5f * (x - y);
            c = fminf(fmaxf(c, -1.f), 0.999f);
            const float t  = fmaf(c, 255.5f, 255.5f);   // (0.5c+0.5)*511
            const float fi = floorf(t);
            const float w  = t - fi;
            const half_t hw   = (half_t)w;
            const half_t homw = (half_t)(1.f - w);
            // row byte offset: (a*512 + i0) * 256 dims * 2B; lane chunk 32B
            const char* base = T2b + ((((a << 9) + (int)fi) << 9) + (e0 << 1));
            const half8 v0a = *reinterpret_cast<const half8*>(base);
            const half8 v0b = *reinterpret_cast<const half8*>(base + 16);
            const half8 v1a = *reinterpret_cast<const half8*>(base + 512);
            const half8 v1b = *reinterpret_cast<const half8*>(base + 528);
            accA = v0a * homw + accA;     // v_pk_fma_f16 x4
            accA = v1a * hw   + accA;
            accB = v0b * homw + accB;
            accB = v1b * hw   + accB;
        }

        float q0 = 0.f, q1 = 0.f, q2 = 0.f;
        #pragma unroll
        for (int d = 0; d < 16; ++d) {
            const half_t a16 = (d < 8) ? accA[d] : accB[d - 8];
            const float arg = fmaf((float)a16, 1.0f, bias[d]);  // v_fma_mix
            const float h = __builtin_amdgcn_sinf(__builtin_amdgcn_fractf(arg));
            q0 = fmaf(h, (float)w2h[0][d >> 3][d & 7], q0);     // v_fma_mix
            q1 = fmaf(h, (float)w2h[1][d >> 3][d & 7], q1);
            q2 = fmaf(h, (float)w2h[2][d >> 3][d & 7], q2);
        }

        // 4-level butterfly within each 16-lane group
        #pragma unroll
        for (int off = 8; off > 0; off >>= 1) {
            q0 += __shfl_xor(q0, off, 64);
            q1 += __shfl_xor(q1, off, 64);
            q2 += __shfl_xor(q2, off, 64);
        }

        if (l16 == 0) {
            out[3 * p + 0] = q0 + ob0;
            out[3 * p + 1] = q1 + ob1;
            out[3 * p + 2] = q2 + ob2;
        }
    }
}

extern "C" void kernel_launch(void* const* d_in, const int* in_sizes, int n_in,
                              void* d_out, int out_size, void* d_ws, size_t ws_size,
                              hipStream_t stream) {
    const float* coords = (const float*)d_in[0];
    const float* tables = (const float*)d_in[1];
    const float* W1     = (const float*)d_in[2];
    const float* b1     = (const float*)d_in[3];
    const float* W2     = (const float*)d_in[4];
    const float* b2     = (const float*)d_in[5];
    float* out = (float*)d_out;

    half_t* T2 = (half_t*)d_ws;   // 2048*256*2B = 1 MiB scratch

    hipLaunchKernelGGL(t2_precompute_kernel, dim3(NROWS / 8), dim3(256), 0, stream,
                       tables, W1, T2);
    hipLaunchKernelGGL(eval_kernel, dim3(2048), dim3(256), 0, stream,
                       coords, T2, b1, W2, b2, out);
}

// Round 5
// 59.620 us; speedup vs baseline: 1.6832x; 1.1131x over previous
//
#include <hip/hip_runtime.h>
#include <hip/hip_bf16.h>
#include <hip/hip_fp16.h>

#define NPTS 262144
#define EMB  256
#define RES  512
#define NROWS (4 * RES)   // 2048 table rows total

typedef _Float16 half_t;
typedef __attribute__((ext_vector_type(8))) _Float16 half8;
typedef __attribute__((ext_vector_type(2))) _Float16 half2v;

// ---------------------------------------------------------------------------
// Kernel 1: T2[a,i,o] = (30/4)/(2pi) * sum_e tables[a,i,e] * W1[o,e], fp16.
// Folds W0=30, the 1/4 axis-mean, AND the 1/(2pi) rev-conversion for v_sin.
// ---------------------------------------------------------------------------
__global__ __launch_bounds__(256) void t2_precompute_kernel(
    const float* __restrict__ tables,   // [4][512][256]
    const float* __restrict__ W1,       // [256][256] (W1[o][e])
    half_t* __restrict__ T2)            // [2048][256] fp16
{
    __shared__ __align__(16) float arow[8][EMB];
    const int row0 = blockIdx.x * 8;
    const int o = threadIdx.x;

    #pragma unroll
    for (int r = 0; r < 8; ++r)
        arow[r][o] = tables[(row0 + r) * EMB + o];
    __syncthreads();

    float acc[8] = {0.f, 0.f, 0.f, 0.f, 0.f, 0.f, 0.f, 0.f};
    const float4* __restrict__ w1v = reinterpret_cast<const float4*>(W1 + o * EMB);
    for (int ec = 0; ec < EMB / 4; ++ec) {
        const float4 w4 = w1v[ec];
        #pragma unroll
        for (int r = 0; r < 8; ++r) {
            const float4 a4 = *reinterpret_cast<const float4*>(&arow[r][ec * 4]);
            acc[r] = fmaf(w4.x, a4.x, acc[r]);
            acc[r] = fmaf(w4.y, a4.y, acc[r]);
            acc[r] = fmaf(w4.z, a4.z, acc[r]);
            acc[r] = fmaf(w4.w, a4.w, acc[r]);
        }
    }
    const float s = 7.5f * 0.15915494309189535f;   // (30/4) / (2*pi)
    #pragma unroll
    for (int r = 0; r < 8; ++r)
        T2[(row0 + r) * EMB + o] = (half_t)(s * acc[r]);
}

// ---------------------------------------------------------------------------
// Kernel 2: 16 lanes/point, 4 points/wave. Lane l16 owns dims
// [8*l16, 8*l16+8) (row half A) and [128+8*l16, +8) (row half B), so every
// 16B load is lane-contiguous (dense 256B/group L2 segments).
// All 16 row loads issued before the lerp (MLP), acc in packed fp16
// initialized with the folded bias; h = v_sin(arg) (rev, no fract needed);
// dots via v_dot2_f32_f16.
// ---------------------------------------------------------------------------
__global__ __launch_bounds__(256, 4) void eval_kernel(
    const float* __restrict__ coords,      // [N][2]
    const half_t* __restrict__ T2,         // [2048][256] fp16
    const float* __restrict__ b1,          // [256]
    const float* __restrict__ W2,          // [3][256]
    const float* __restrict__ b2,          // [3]
    float* __restrict__ out)               // [N][3]
{
    const int lane = threadIdx.x & 63;
    const int g    = lane >> 4;            // point slot 0..3 within wave
    const int l16  = lane & 15;            // lane within 16-lane group
    const int dA   = l16 * 8;              // dims dA..dA+7   (row half A)
    const int dB   = 128 + l16 * 8;        // dims dB..dB+7   (row half B)

    const int wave   = blockIdx.x * 4 + (threadIdx.x >> 6);
    const int nwaves = gridDim.x * 4;

    const float sb = 30.f * 0.15915494309189535f;  // bias scale -> revolutions
    half8 biasA, biasB;
    #pragma unroll
    for (int i = 0; i < 8; ++i) {
        biasA[i] = (half_t)(sb * b1[dA + i]);
        biasB[i] = (half_t)(sb * b1[dB + i]);
    }
    half2v w2p[3][8];   // [out j][pair k]: k<4 -> A dims (2k,2k+1); k>=4 -> B
    #pragma unroll
    for (int j = 0; j < 3; ++j)
        #pragma unroll
        for (int k = 0; k < 4; ++k) {
            w2p[j][k][0]     = (half_t)W2[j * EMB + dA + 2 * k];
            w2p[j][k][1]     = (half_t)W2[j * EMB + dA + 2 * k + 1];
            w2p[j][4 + k][0] = (half_t)W2[j * EMB + dB + 2 * k];
            w2p[j][4 + k][1] = (half_t)W2[j * EMB + dB + 2 * k + 1];
        }
    const float ob0 = b2[0], ob1 = b2[1], ob2 = b2[2];
    const char* __restrict__ T2b = reinterpret_cast<const char*>(T2) + (l16 << 4);

    for (int pq = wave; pq < NPTS / 4; pq += nwaves) {
        const int p = 4 * pq + g;
        const float2 cf = *reinterpret_cast<const float2*>(coords + 2 * p);
        const float x = fminf(fmaxf(cf.x, -1.f), 1.f);
        const float y = fminf(fmaxf(cf.y, -1.f), 1.f);

        int rb[4];
        half_t hw[4], homw[4];
        #pragma unroll
        for (int a = 0; a < 4; ++a) {
            float c = (a == 0) ? x : (a == 1) ? y
                    : (a == 2) ? 0.5f * (x + y) : 0.5f * (x - y);
            c = fminf(fmaxf(c, -1.f), 0.999f);
            const float t  = fmaf(c, 255.5f, 255.5f);   // (0.5c+0.5)*511
            const float fi = floorf(t);
            const float w  = t - fi;
            hw[a]   = (half_t)w;
            homw[a] = (half_t)(1.f - w);
            rb[a]   = (((a << 9) + (int)fi) << 9);      // row byte offset
        }

        // issue all 16 dense 16B loads (A/B halves of rows i0 and i0+1)
        half8 A0[4], B0[4], A1[4], B1[4];
        #pragma unroll
        for (int a = 0; a < 4; ++a) {
            const char* base = T2b + rb[a];
            A0[a] = *reinterpret_cast<const half8*>(base);
            B0[a] = *reinterpret_cast<const half8*>(base + 256);
            A1[a] = *reinterpret_cast<const half8*>(base + 512);
            B1[a] = *reinterpret_cast<const half8*>(base + 768);
        }

        half8 accA = biasA, accB = biasB;
        #pragma unroll
        for (int a = 0; a < 4; ++a) {
            accA = A0[a] * homw[a] + accA;    // v_pk_fma_f16
            accA = A1[a] * hw[a]   + accA;
            accB = B0[a] * homw[a] + accB;
            accB = B1[a] * hw[a]   + accB;
        }

        float q0 = 0.f, q1 = 0.f, q2 = 0.f;
        #pragma unroll
        for (int k = 0; k < 4; ++k) {
            const float s0 = __builtin_amdgcn_sinf((float)accA[2 * k]);
            const float s1 = __builtin_amdgcn_sinf((float)accA[2 * k + 1]);
#if __has_builtin(__builtin_amdgcn_fdot2)
            const half2v hp = __builtin_bit_cast(half2v, __builtin_amdgcn_cvt_pkrtz(s0, s1));
            q0 = __builtin_amdgcn_fdot2(hp, w2p[0][k], q0, false);
            q1 = __builtin_amdgcn_fdot2(hp, w2p[1][k], q1, false);
            q2 = __builtin_amdgcn_fdot2(hp, w2p[2][k], q2, false);
#else
            q0 = fmaf(s0, (float)w2p[0][k][0], fmaf(s1, (float)w2p[0][k][1], q0));
            q1 = fmaf(s0, (float)w2p[1][k][0], fmaf(s1, (float)w2p[1][k][1], q1));
            q2 = fmaf(s0, (float)w2p[2][k][0], fmaf(s1, (float)w2p[2][k][1], q2));
#endif
        }
        #pragma unroll
        for (int k = 0; k < 4; ++k) {
            const float s0 = __builtin_amdgcn_sinf((float)accB[2 * k]);
            const float s1 = __builtin_amdgcn_sinf((float)accB[2 * k + 1]);
#if __has_builtin(__builtin_amdgcn_fdot2)
            const half2v hp = __builtin_bit_cast(half2v, __builtin_amdgcn_cvt_pkrtz(s0, s1));
            q0 = __builtin_amdgcn_fdot2(hp, w2p[0][4 + k], q0, false);
            q1 = __builtin_amdgcn_fdot2(hp, w2p[1][4 + k], q1, false);
            q2 = __builtin_amdgcn_fdot2(hp, w2p[2][4 + k], q2, false);
#else
            q0 = fmaf(s0, (float)w2p[0][4 + k][0], fmaf(s1, (float)w2p[0][4 + k][1], q0));
            q1 = fmaf(s0, (float)w2p[1][4 + k][0], fmaf(s1, (float)w2p[1][4 + k][1], q1));
            q2 = fmaf(s0, (float)w2p[2][4 + k][0], fmaf(s1, (float)w2p[2][4 + k][1], q2));
#endif
        }

        // 4-level butterfly within each 16-lane group
        #pragma unroll
        for (int off = 8; off > 0; off >>= 1) {
            q0 += __shfl_xor(q0, off, 64);
            q1 += __shfl_xor(q1, off, 64);
            q2 += __shfl_xor(q2, off, 64);
        }

        if (l16 == 0) {
            out[3 * p + 0] = q0 + ob0;
            out[3 * p + 1] = q1 + ob1;
            out[3 * p + 2] = q2 + ob2;
        }
    }
}

extern "C" void kernel_launch(void* const* d_in, const int* in_sizes, int n_in,
                              void* d_out, int out_size, void* d_ws, size_t ws_size,
                              hipStream_t stream) {
    const float* coords = (const float*)d_in[0];
    const float* tables = (const float*)d_in[1];
    const float* W1     = (const float*)d_in[2];
    const float* b1     = (const float*)d_in[3];
    const float* W2     = (const float*)d_in[4];
    const float* b2     = (const float*)d_in[5];
    float* out = (float*)d_out;

    half_t* T2 = (half_t*)d_ws;   // 2048*256*2B = 1 MiB scratch

    hipLaunchKernelGGL(t2_precompute_kernel, dim3(NROWS / 8), dim3(256), 0, stream,
                       tables, W1, T2);
    hipLaunchKernelGGL(eval_kernel, dim3(2048), dim3(256), 0, stream,
                       coords, T2, b1, W2, b2, out);
}